// Round 9
// baseline (280.805 us; speedup 1.0000x reference)
//
#include <hip/hip_runtime.h>
#include <hip/hip_fp16.h>

#define N_NODES 500000
#define N_CELLS 1000000
#define N_PTS   8000000

typedef float f32x4 __attribute__((ext_vector_type(4)));

// ---------------- Pass 0: pack nodal (2,N) f32 -> interleaved half2 table (2 MB) ----------------
__global__ __launch_bounds__(256) void pack_nodal_h2_kernel(
    const float* __restrict__ nodal,   // (2, N_NODES)
    __half2*     __restrict__ nodal_h2)// (N_NODES,)
{
    const int n0 = (blockIdx.x * blockDim.x + threadIdx.x) * 4;
    if (n0 >= N_NODES) return;
    const f32x4 a = *reinterpret_cast<const f32x4*>(nodal + n0);
    const f32x4 b = *reinterpret_cast<const f32x4*>(nodal + N_NODES + n0);
    __half2 h[4];
    h[0] = __floats2half2_rn(a.x, b.x);
    h[1] = __floats2half2_rn(a.y, b.y);
    h[2] = __floats2half2_rn(a.z, b.z);
    h[3] = __floats2half2_rn(a.w, b.w);
    *reinterpret_cast<f32x4*>(nodal_h2 + n0) = *reinterpret_cast<f32x4*>(h);
}

// ---------------- Pass 1: gather per-cell nodal values into f32 64B rows (2 cells/thread) ----------------
// cellvals[c] is a 64B row: [v0(n0), v1(n0), ..., v0(n5), v1(n5), pad*4]
__global__ __launch_bounds__(256) void gather_cellvals_kernel(
    const __half2* __restrict__ nodal_h2, // (N_NODES,) interleaved (v0,v1), 2MB L2-resident
    const int*     __restrict__ conn,     // (N_CELLS, 6), 1-based
    float*         __restrict__ cellvals) // (N_CELLS, 16) f32
{
    const int t  = blockIdx.x * blockDim.x + threadIdx.x;
    const int c0 = t * 2;
    if (c0 >= N_CELLS) return;

    // two cells: 12 ints = 3 x int4 (16B aligned since c0 even), fully coalesced
    const int4* cp = reinterpret_cast<const int4*>(conn + (size_t)c0 * 6);
    const int4 i0 = cp[0], i1 = cp[1], i2 = cp[2];
    const int n[12] = { i0.x, i0.y, i0.z, i0.w, i1.x, i1.y,
                        i1.z, i1.w, i2.x, i2.y, i2.z, i2.w };

    // 12 independent 4B gathers from the 2MB L2-resident table
    float2 v[12];
    #pragma unroll
    for (int k = 0; k < 12; ++k) {
        v[k] = __half22float2(nodal_h2[n[k] - 1]);
    }

    // NT stores: write-once full 64B lines; keep L2 clean for nodal_h2
    #pragma unroll
    for (int cc = 0; cc < 2; ++cc) {
        f32x4* dst = reinterpret_cast<f32x4*>(cellvals + (size_t)(c0 + cc) * 16);
        const float2* vv = v + cc * 6;
        f32x4 d0; d0.x = vv[0].x; d0.y = vv[0].y; d0.z = vv[1].x; d0.w = vv[1].y;
        f32x4 d1; d1.x = vv[2].x; d1.y = vv[2].y; d1.z = vv[3].x; d1.w = vv[3].y;
        f32x4 d2; d2.x = vv[4].x; d2.y = vv[4].y; d2.z = vv[5].x; d2.w = vv[5].y;
        f32x4 d3; d3.x = 0.f; d3.y = 0.f; d3.z = 0.f; d3.w = 0.f;
        __builtin_nontemporal_store(d0, dst + 0);
        __builtin_nontemporal_store(d1, dst + 1);
        __builtin_nontemporal_store(d2, dst + 2);
        __builtin_nontemporal_store(d3, dst + 3);
    }
}

// ---------------- Pass 2: per-point interpolation (2 points/thread, r2 verbatim) ----------------
__global__ __launch_bounds__(256) void interp2d_cellvals_kernel(
    const float* __restrict__ cellvals, // (N_CELLS, 16)
    const float* __restrict__ sf,       // (N_PTS, 6)
    const int*   __restrict__ cid,      // (N_PTS,)
    float* __restrict__ out)            // (2, N_PTS)
{
    const int t  = blockIdx.x * blockDim.x + threadIdx.x;
    const int p0 = t * 2;
    if (p0 >= N_PTS) return;

    const int2 c = *reinterpret_cast<const int2*>(cid + p0);

    // 12 shape-function floats for points p0, p0+1 (16B aligned: 48B stride)
    const float4* sfp = reinterpret_cast<const float4*>(sf + (size_t)p0 * 6);
    const float4 s0 = sfp[0];
    const float4 s1 = sfp[1];
    const float4 s2 = sfp[2];

    // issue both cell rows up front (each = one 64B line)
    const float4* r0 = reinterpret_cast<const float4*>(cellvals + (size_t)c.x * 16);
    const float4* r1 = reinterpret_cast<const float4*>(cellvals + (size_t)c.y * 16);
    const float4 q00 = r0[0], q01 = r0[1], q02 = r0[2];
    const float4 q10 = r1[0], q11 = r1[1], q12 = r1[2];

    float a0, a1, b0, b1;
    a0 = s0.x * q00.x; a1 = s0.x * q00.y;
    a0 = fmaf(s0.y, q00.z, a0); a1 = fmaf(s0.y, q00.w, a1);
    a0 = fmaf(s0.z, q01.x, a0); a1 = fmaf(s0.z, q01.y, a1);
    a0 = fmaf(s0.w, q01.z, a0); a1 = fmaf(s0.w, q01.w, a1);
    a0 = fmaf(s1.x, q02.x, a0); a1 = fmaf(s1.x, q02.y, a1);
    a0 = fmaf(s1.y, q02.z, a0); a1 = fmaf(s1.y, q02.w, a1);

    b0 = s1.z * q10.x; b1 = s1.z * q10.y;
    b0 = fmaf(s1.w, q10.z, b0); b1 = fmaf(s1.w, q10.w, b1);
    b0 = fmaf(s2.x, q11.x, b0); b1 = fmaf(s2.x, q11.y, b1);
    b0 = fmaf(s2.y, q11.z, b0); b1 = fmaf(s2.y, q11.w, b1);
    b0 = fmaf(s2.z, q12.x, b0); b1 = fmaf(s2.z, q12.y, b1);
    b0 = fmaf(s2.w, q12.z, b0); b1 = fmaf(s2.w, q12.w, b1);

    *reinterpret_cast<float2*>(out + p0)         = make_float2(a0, b0);
    *reinterpret_cast<float2*>(out + N_PTS + p0) = make_float2(a1, b1);
}

// ---------------- Fallback (round-1 direct kernel) ----------------
__global__ __launch_bounds__(256) void interp2d_direct_kernel(
    const float* __restrict__ nodal,
    const float* __restrict__ sf,
    const int*   __restrict__ conn,
    const int*   __restrict__ cid,
    float* __restrict__ out)
{
    const int t  = blockIdx.x * blockDim.x + threadIdx.x;
    const int p0 = t * 2;
    if (p0 >= N_PTS) return;

    const int2 c = *reinterpret_cast<const int2*>(cid + p0);
    const float4* sfp = reinterpret_cast<const float4*>(sf + (size_t)p0 * 6);
    const float4 s0 = sfp[0];
    const float4 s1 = sfp[1];
    const float4 s2 = sfp[2];
    const float w0[6] = { s0.x, s0.y, s0.z, s0.w, s1.x, s1.y };
    const float w1[6] = { s1.z, s1.w, s2.x, s2.y, s2.z, s2.w };

    float o00 = 0.f, o01 = 0.f, o10 = 0.f, o11 = 0.f;
    {
        const int* cr = conn + (size_t)c.x * 6;
        #pragma unroll
        for (int k = 0; k < 6; ++k) {
            const int node = cr[k] - 1;
            o00 = fmaf(w0[k], nodal[node], o00);
            o01 = fmaf(w0[k], nodal[N_NODES + node], o01);
        }
    }
    {
        const int* cr = conn + (size_t)c.y * 6;
        #pragma unroll
        for (int k = 0; k < 6; ++k) {
            const int node = cr[k] - 1;
            o10 = fmaf(w1[k], nodal[node], o10);
            o11 = fmaf(w1[k], nodal[N_NODES + node], o11);
        }
    }
    *reinterpret_cast<float2*>(out + p0)         = make_float2(o00, o10);
    *reinterpret_cast<float2*>(out + N_PTS + p0) = make_float2(o01, o11);
}

extern "C" void kernel_launch(void* const* d_in, const int* in_sizes, int n_in,
                              void* d_out, int out_size, void* d_ws, size_t ws_size,
                              hipStream_t stream) {
    const float* nodal = (const float*)d_in[0];  // (2, N_NODES)
    const float* sf    = (const float*)d_in[1];  // (N_PTS, 6)
    const int*   conn  = (const int*)d_in[2];    // (N_CELLS, 6)
    const int*   cid   = (const int*)d_in[3];    // (N_PTS,)
    float* out = (float*)d_out;                  // (2, N_PTS)

    const size_t cellvals_bytes = (size_t)N_CELLS * 16 * sizeof(float);  // 64 MB
    const size_t nodal_h2_bytes = (size_t)N_NODES * sizeof(__half2);     // 2 MB

    if (ws_size >= cellvals_bytes + nodal_h2_bytes) {
        float*   cellvals = (float*)d_ws;
        __half2* nodal_h2 = (__half2*)((char*)d_ws + cellvals_bytes);
        {
            const int threads = 256;
            const int blocks = (N_NODES / 4 + threads - 1) / threads;
            pack_nodal_h2_kernel<<<blocks, threads, 0, stream>>>(nodal, nodal_h2);
        }
        {
            const int threads = 256;
            const int blocks = (N_CELLS / 2 + threads - 1) / threads;
            gather_cellvals_kernel<<<blocks, threads, 0, stream>>>(nodal_h2, conn, cellvals);
        }
        {
            const int threads = 256;
            const int blocks = (N_PTS / 2 + threads - 1) / threads;
            interp2d_cellvals_kernel<<<blocks, threads, 0, stream>>>(cellvals, sf, cid, out);
        }
    } else {
        const int threads = 256;
        const int blocks = (N_PTS / 2 + threads - 1) / threads;
        interp2d_direct_kernel<<<blocks, threads, 0, stream>>>(nodal, sf, conn, cid, out);
    }
}

// Round 10
// 225.548 us; speedup vs baseline: 1.2450x; 1.2450x over previous
//
#include <hip/hip_runtime.h>
#include <hip/hip_fp16.h>

#define N_NODES 500000
#define N_CELLS 1000000
#define N_PTS   8000000

typedef float f32x4 __attribute__((ext_vector_type(4)));

// ---------------- Pass 0: pack nodal (2,N) f32 -> interleaved half2 table (2 MB) ----------------
__global__ __launch_bounds__(256) void pack_nodal_h2_kernel(
    const float* __restrict__ nodal,   // (2, N_NODES)
    __half2*     __restrict__ nodal_h2)// (N_NODES,)
{
    const int n0 = (blockIdx.x * blockDim.x + threadIdx.x) * 4;
    if (n0 >= N_NODES) return;
    const f32x4 a = *reinterpret_cast<const f32x4*>(nodal + n0);
    const f32x4 b = *reinterpret_cast<const f32x4*>(nodal + N_NODES + n0);
    __half2 h[4];
    h[0] = __floats2half2_rn(a.x, b.x);
    h[1] = __floats2half2_rn(a.y, b.y);
    h[2] = __floats2half2_rn(a.z, b.z);
    h[3] = __floats2half2_rn(a.w, b.w);
    *reinterpret_cast<f32x4*>(nodal_h2 + n0) = *reinterpret_cast<f32x4*>(h);
}

// ---------------- Pass 1: gather per-cell nodal values into f32 64B rows (2 cells/thread) ----------------
// cellvals[c] is a 64B row: [v0(n0), v1(n0), ..., v0(n5), v1(n5), pad*4]
// Regular stores on purpose: the 64MB table must land in L2/LLC for pass 2 (r9 lesson).
__global__ __launch_bounds__(256) void gather_cellvals_kernel(
    const __half2* __restrict__ nodal_h2, // (N_NODES,) interleaved (v0,v1), 2MB L2-resident
    const int*     __restrict__ conn,     // (N_CELLS, 6), 1-based
    float*         __restrict__ cellvals) // (N_CELLS, 16) f32
{
    const int t  = blockIdx.x * blockDim.x + threadIdx.x;
    const int c0 = t * 2;
    if (c0 >= N_CELLS) return;

    // two cells: 12 ints = 3 x int4 (16B aligned since c0 even), fully coalesced
    const int4* cp = reinterpret_cast<const int4*>(conn + (size_t)c0 * 6);
    const int4 i0 = cp[0], i1 = cp[1], i2 = cp[2];
    const int n[12] = { i0.x, i0.y, i0.z, i0.w, i1.x, i1.y,
                        i1.z, i1.w, i2.x, i2.y, i2.z, i2.w };

    // 12 independent 4B gathers from the 2MB L2-resident table
    float2 v[12];
    #pragma unroll
    for (int k = 0; k < 12; ++k) {
        v[k] = __half22float2(nodal_h2[n[k] - 1]);
    }

    #pragma unroll
    for (int cc = 0; cc < 2; ++cc) {
        float4* dst = reinterpret_cast<float4*>(cellvals + (size_t)(c0 + cc) * 16);
        const float2* vv = v + cc * 6;
        dst[0] = make_float4(vv[0].x, vv[0].y, vv[1].x, vv[1].y);
        dst[1] = make_float4(vv[2].x, vv[2].y, vv[3].x, vv[3].y);
        dst[2] = make_float4(vv[4].x, vv[4].y, vv[5].x, vv[5].y);
        dst[3] = make_float4(0.f, 0.f, 0.f, 0.f);   // full 64B line write (no RMW)
    }
}

// ---------------- Pass 2: per-point interpolation (2 points/thread, r2/r8 verbatim) ----------------
__global__ __launch_bounds__(256) void interp2d_cellvals_kernel(
    const float* __restrict__ cellvals, // (N_CELLS, 16)
    const float* __restrict__ sf,       // (N_PTS, 6)
    const int*   __restrict__ cid,      // (N_PTS,)
    float* __restrict__ out)            // (2, N_PTS)
{
    const int t  = blockIdx.x * blockDim.x + threadIdx.x;
    const int p0 = t * 2;
    if (p0 >= N_PTS) return;

    const int2 c = *reinterpret_cast<const int2*>(cid + p0);

    // 12 shape-function floats for points p0, p0+1 (16B aligned: 48B stride)
    const float4* sfp = reinterpret_cast<const float4*>(sf + (size_t)p0 * 6);
    const float4 s0 = sfp[0];
    const float4 s1 = sfp[1];
    const float4 s2 = sfp[2];

    // issue both cell rows up front (each = one 64B line)
    const float4* r0 = reinterpret_cast<const float4*>(cellvals + (size_t)c.x * 16);
    const float4* r1 = reinterpret_cast<const float4*>(cellvals + (size_t)c.y * 16);
    const float4 q00 = r0[0], q01 = r0[1], q02 = r0[2];
    const float4 q10 = r1[0], q11 = r1[1], q12 = r1[2];

    float a0, a1, b0, b1;
    a0 = s0.x * q00.x; a1 = s0.x * q00.y;
    a0 = fmaf(s0.y, q00.z, a0); a1 = fmaf(s0.y, q00.w, a1);
    a0 = fmaf(s0.z, q01.x, a0); a1 = fmaf(s0.z, q01.y, a1);
    a0 = fmaf(s0.w, q01.z, a0); a1 = fmaf(s0.w, q01.w, a1);
    a0 = fmaf(s1.x, q02.x, a0); a1 = fmaf(s1.x, q02.y, a1);
    a0 = fmaf(s1.y, q02.z, a0); a1 = fmaf(s1.y, q02.w, a1);

    b0 = s1.z * q10.x; b1 = s1.z * q10.y;
    b0 = fmaf(s1.w, q10.z, b0); b1 = fmaf(s1.w, q10.w, b1);
    b0 = fmaf(s2.x, q11.x, b0); b1 = fmaf(s2.x, q11.y, b1);
    b0 = fmaf(s2.y, q11.z, b0); b1 = fmaf(s2.y, q11.w, b1);
    b0 = fmaf(s2.z, q12.x, b0); b1 = fmaf(s2.z, q12.y, b1);
    b0 = fmaf(s2.w, q12.z, b0); b1 = fmaf(s2.w, q12.w, b1);

    *reinterpret_cast<float2*>(out + p0)         = make_float2(a0, b0);
    *reinterpret_cast<float2*>(out + N_PTS + p0) = make_float2(a1, b1);
}

// ---------------- Fallback (round-1 direct kernel) ----------------
__global__ __launch_bounds__(256) void interp2d_direct_kernel(
    const float* __restrict__ nodal,
    const float* __restrict__ sf,
    const int*   __restrict__ conn,
    const int*   __restrict__ cid,
    float* __restrict__ out)
{
    const int t  = blockIdx.x * blockDim.x + threadIdx.x;
    const int p0 = t * 2;
    if (p0 >= N_PTS) return;

    const int2 c = *reinterpret_cast<const int2*>(cid + p0);
    const float4* sfp = reinterpret_cast<const float4*>(sf + (size_t)p0 * 6);
    const float4 s0 = sfp[0];
    const float4 s1 = sfp[1];
    const float4 s2 = sfp[2];
    const float w0[6] = { s0.x, s0.y, s0.z, s0.w, s1.x, s1.y };
    const float w1[6] = { s1.z, s1.w, s2.x, s2.y, s2.z, s2.w };

    float o00 = 0.f, o01 = 0.f, o10 = 0.f, o11 = 0.f;
    {
        const int* cr = conn + (size_t)c.x * 6;
        #pragma unroll
        for (int k = 0; k < 6; ++k) {
            const int node = cr[k] - 1;
            o00 = fmaf(w0[k], nodal[node], o00);
            o01 = fmaf(w0[k], nodal[N_NODES + node], o01);
        }
    }
    {
        const int* cr = conn + (size_t)c.y * 6;
        #pragma unroll
        for (int k = 0; k < 6; ++k) {
            const int node = cr[k] - 1;
            o10 = fmaf(w1[k], nodal[node], o10);
            o11 = fmaf(w1[k], nodal[N_NODES + node], o11);
        }
    }
    *reinterpret_cast<float2*>(out + p0)         = make_float2(o00, o10);
    *reinterpret_cast<float2*>(out + N_PTS + p0) = make_float2(o01, o11);
}

extern "C" void kernel_launch(void* const* d_in, const int* in_sizes, int n_in,
                              void* d_out, int out_size, void* d_ws, size_t ws_size,
                              hipStream_t stream) {
    const float* nodal = (const float*)d_in[0];  // (2, N_NODES)
    const float* sf    = (const float*)d_in[1];  // (N_PTS, 6)
    const int*   conn  = (const int*)d_in[2];    // (N_CELLS, 6)
    const int*   cid   = (const int*)d_in[3];    // (N_PTS,)
    float* out = (float*)d_out;                  // (2, N_PTS)

    const size_t cellvals_bytes = (size_t)N_CELLS * 16 * sizeof(float);  // 64 MB
    const size_t nodal_h2_bytes = (size_t)N_NODES * sizeof(__half2);     // 2 MB

    if (ws_size >= cellvals_bytes + nodal_h2_bytes) {
        float*   cellvals = (float*)d_ws;
        __half2* nodal_h2 = (__half2*)((char*)d_ws + cellvals_bytes);
        {
            const int threads = 256;
            const int blocks = (N_NODES / 4 + threads - 1) / threads;
            pack_nodal_h2_kernel<<<blocks, threads, 0, stream>>>(nodal, nodal_h2);
        }
        {
            const int threads = 256;
            const int blocks = (N_CELLS / 2 + threads - 1) / threads;
            gather_cellvals_kernel<<<blocks, threads, 0, stream>>>(nodal_h2, conn, cellvals);
        }
        {
            const int threads = 256;
            const int blocks = (N_PTS / 2 + threads - 1) / threads;
            interp2d_cellvals_kernel<<<blocks, threads, 0, stream>>>(cellvals, sf, cid, out);
        }
    } else {
        const int threads = 256;
        const int blocks = (N_PTS / 2 + threads - 1) / threads;
        interp2d_direct_kernel<<<blocks, threads, 0, stream>>>(nodal, sf, conn, cid, out);
    }
}